// Round 4
// baseline (180.729 us; speedup 1.0000x reference)
//
#include <hip/hip_runtime.h>
#include <math.h>

#define Bn 64
#define Pn 8732
#define Cn 21
#define NMAXn 50
#define PX 35  // ceil(Pn/256)
#define Wn 16  // waves per 1024-thread block

// ---------------------------------------------------------------------------
// K1: per-batch best-prior argmax. One block per batch; corner-form priors
// staged ONCE in LDS (139.7 KB) instead of 3200 blocks x 140 KB of L2 reads.
// Per-n: all 16 waves scan their prior slices, wave-reduce via shfl (no
// block sync inside the loop), per-wave winners to LDS; one sync; phase 2
// combines 16 winners per n. Tie-break = smallest prior index (argmax).
// ---------------------------------------------------------------------------
__global__ __launch_bounds__(1024) void k_bp(const float* __restrict__ labels,
                                             const int* __restrict__ objc,
                                             const float* __restrict__ priors,
                                             int* __restrict__ bp) {
    const int b = blockIdx.x;
    const int tid = threadIdx.x;
    const int lane = tid & 63, wid = tid >> 6;
    __shared__ float4 pc[Pn];          // 139712 B corner-form priors
    __shared__ float lab[NMAXn * 5];   // 1000 B
    __shared__ float wv[NMAXn][Wn];    // 3200 B
    __shared__ int wi[NMAXn][Wn];      // 3200 B
    const int cnt = objc[b];
    for (int p = tid; p < Pn; p += 1024) {
        const float4 pr = reinterpret_cast<const float4*>(priors)[p];
        pc[p] = make_float4(pr.x - 0.5f * pr.z, pr.y - 0.5f * pr.w,
                            pr.x + 0.5f * pr.z, pr.y + 0.5f * pr.w);
    }
    for (int i = tid; i < NMAXn * 5; i += 1024) lab[i] = labels[b * NMAXn * 5 + i];
    __syncthreads();
    for (int n = 0; n < cnt; ++n) {
        const float gx0 = lab[n * 5 + 0], gy0 = lab[n * 5 + 1];
        const float gx1 = lab[n * 5 + 2], gy1 = lab[n * 5 + 3];
        const float ga = (gx1 - gx0) * (gy1 - gy0);
        float best = -1.0f;
        int bidx = 0;
        for (int p = tid; p < Pn; p += 1024) {  // ascending p: strict > keeps min idx
            const float4 c = pc[p];
            const float lx = fmaxf(gx0, c.x), ly = fmaxf(gy0, c.y);
            const float rx = fminf(gx1, c.z), ry = fminf(gy1, c.w);
            const float w = fmaxf(rx - lx, 0.0f), h = fmaxf(ry - ly, 0.0f);
            const float inter = w * h;
            const float pa = (c.z - c.x) * (c.w - c.y);
            const float v = inter / (ga + pa - inter);
            if (v > best) { best = v; bidx = p; }
        }
        for (int off = 32; off > 0; off >>= 1) {
            const float ov = __shfl_down(best, off);
            const int oi = __shfl_down(bidx, off);
            if (ov > best || (ov == best && oi < bidx)) { best = ov; bidx = oi; }
        }
        if (lane == 0) { wv[n][wid] = best; wi[n][wid] = bidx; }
    }
    __syncthreads();
    if (tid < cnt) {
        float best = wv[tid][0];
        int bidx = wi[tid][0];
#pragma unroll
        for (int w = 1; w < Wn; ++w) {
            const float ov = wv[tid][w];
            const int oi = wi[tid][w];
            if (ov > best || (ov == best && oi < bidx)) { best = ov; bidx = oi; }
        }
        bp[b * NMAXn + tid] = bidx;
    }
}

// ---------------------------------------------------------------------------
// K2: main pass. Best-GT match computed INLINE (merged with forced-override
// scan in one loop over cnt): forced (any n with bp[n]==p, last n wins) takes
// precedence over IoU argmax, exactly matching the reference's scatter. Then
// lse, nll, fused smooth-L1, pos-masked mining score lc, per-block partials
// via plain stores. Block (0,0) resets the done counter for K3.
// ---------------------------------------------------------------------------
__global__ __launch_bounds__(256) void k_main(const float* __restrict__ conf,
                                              const float* __restrict__ loc,
                                              const float* __restrict__ priors,
                                              const float* __restrict__ labels,
                                              const int* __restrict__ objc,
                                              const int* __restrict__ bp,
                                              float* __restrict__ lc,
                                              float* __restrict__ part_loc,
                                              float* __restrict__ part_nll,
                                              int* __restrict__ part_np,
                                              int* __restrict__ done) {
    const int b = blockIdx.y;
    const int px = blockIdx.x;
    const int p0 = px * 256;
    const int tid = threadIdx.x;
    const int rows = min(256, Pn - p0);
    const int p = p0 + ((tid < rows) ? tid : 0);
    const size_t gi = (size_t)b * Pn + p;

    if (b == 0 && px == 0 && tid == 0) *done = 0;  // ordered before K3 by kernel boundary

    __shared__ float sconf[256 * Cn];
    __shared__ float lab[NMAXn * 5];
    __shared__ int sbp[NMAXn];
    __shared__ int cnt_s;
    const float4* src = reinterpret_cast<const float4*>(conf + ((size_t)b * Pn + p0) * Cn);
    const int n4 = rows * Cn / 4;  // rows*21 divisible by 4 for rows in {256,28}
    for (int i = tid; i < n4; i += 256) reinterpret_cast<float4*>(sconf)[i] = src[i];
    for (int i = tid; i < NMAXn * 5; i += 256) lab[i] = labels[b * NMAXn * 5 + i];
    if (tid < NMAXn) sbp[tid] = bp[b * NMAXn + tid];
    if (tid == 0) cnt_s = objc[b];
    __syncthreads();

    float my_loc = 0.0f, my_nll = 0.0f;
    int my_np = 0;
    if (tid < rows) {
        const int cnt = cnt_s;
        const float4 pr = reinterpret_cast<const float4*>(priors)[p];
        const float px0 = pr.x - 0.5f * pr.z, py0 = pr.y - 0.5f * pr.w;
        const float px1 = pr.x + 0.5f * pr.z, py1 = pr.y + 0.5f * pr.w;
        const float parea = (px1 - px0) * (py1 - py0);
        float best = -1.0f;
        int bidx = 0, fidx = -1;
        for (int n = 0; n < cnt; ++n) {
            const float gx0 = lab[n * 5 + 0], gy0 = lab[n * 5 + 1];
            const float gx1 = lab[n * 5 + 2], gy1 = lab[n * 5 + 3];
            const float lx = fmaxf(gx0, px0), ly = fmaxf(gy0, py0);
            const float rx = fminf(gx1, px1), ry = fminf(gy1, py1);
            const float w = fmaxf(rx - lx, 0.0f), h = fmaxf(ry - ly, 0.0f);
            const float inter = w * h;
            const float ga = (gx1 - gx0) * (gy1 - gy0);
            const float v = inter / (ga + parea - inter);
            if (v > best) { best = v; bidx = n; }  // strict >: first-occurrence argmax
            if (sbp[n] == p) fidx = n;             // ascending: last forced n wins
        }
        const int ti = (fidx >= 0) ? fidx : bidx;
        const int fl = (fidx >= 0) || (best >= 0.5f);
        const int ct = fl ? ((int)lab[ti * 5 + 4] + 1) : 0;
        const float* row = sconf + tid * Cn;  // stride 21: odd -> conflict-benign
        float m = row[0];
#pragma unroll
        for (int j = 1; j < Cn; ++j) m = fmaxf(m, row[j]);
        float s2 = 0.0f;
#pragma unroll
        for (int j = 0; j < Cn; ++j) s2 += __expf(row[j] - m);
        const float nll = __logf(s2) + m - row[ct];
        if (ct > 0) {
            lc[gi] = 0.0f;
            my_np = 1;
            my_nll = nll;
            const float gx0 = lab[ti * 5 + 0], gy0 = lab[ti * 5 + 1];
            const float gx1 = lab[ti * 5 + 2], gy1 = lab[ti * 5 + 3];
            const float tx = ((gx0 + gx1) * 0.5f - pr.x) / (0.1f * pr.z);
            const float ty = ((gy0 + gy1) * 0.5f - pr.y) / (0.1f * pr.w);
            const float tw = __logf((gx1 - gx0) / pr.z) * 5.0f;  // /0.2
            const float th = __logf((gy1 - gy0) / pr.w) * 5.0f;
            const float4 l = reinterpret_cast<const float4*>(loc)[gi];
            float d;
            d = fabsf(l.x - tx); my_loc += (d < 1.0f) ? 0.5f * d * d : d - 0.5f;
            d = fabsf(l.y - ty); my_loc += (d < 1.0f) ? 0.5f * d * d : d - 0.5f;
            d = fabsf(l.z - tw); my_loc += (d < 1.0f) ? 0.5f * d * d : d - 0.5f;
            d = fabsf(l.w - th); my_loc += (d < 1.0f) ? 0.5f * d * d : d - 0.5f;
        } else {
            lc[gi] = nll;
        }
    }
    for (int off = 32; off > 0; off >>= 1) {
        my_loc += __shfl_down(my_loc, off);
        my_nll += __shfl_down(my_nll, off);
        my_np += __shfl_down(my_np, off);
    }
    __shared__ float rl[4], rn[4];
    __shared__ int rp[4];
    const int wid = tid >> 6, lane = tid & 63;
    if (lane == 0) { rl[wid] = my_loc; rn[wid] = my_nll; rp[wid] = my_np; }
    __syncthreads();
    if (tid == 0) {
        const int g = b * PX + px;
        part_loc[g] = rl[0] + rl[1] + rl[2] + rl[3];
        part_nll[g] = rn[0] + rn[1] + rn[2] + rn[3];
        part_np[g] = rp[0] + rp[1] + rp[2] + rp[3];
    }
}

// ---------------------------------------------------------------------------
// K3: per-batch hard-negative top-k sum. 1024 threads. Bisection on float
// bits (31 iters, exact); per-iter: scan LDS, wave shfl-reduce, parity-
// buffered per-wave slots, ONE syncthreads. Fused final reduce via done
// counter (last of 64 blocks reduces partials and writes out).
// ---------------------------------------------------------------------------
__global__ __launch_bounds__(1024) void k_neg(const float* __restrict__ lc,
                                              const float* __restrict__ part_loc,
                                              const float* __restrict__ part_nll,
                                              const int* __restrict__ part_np,
                                              float* __restrict__ negsum,
                                              int* __restrict__ done,
                                              float* __restrict__ out) {
    const int b = blockIdx.x;
    const int tid = threadIdx.x;
    const int lane = tid & 63, wid = tid >> 6;
    __shared__ float s[Pn];  // 34928 B
    __shared__ int redc[2][Wn];
    __shared__ float redf[Wn], redf2[Wn];
    __shared__ int redi[Wn];
    __shared__ int np_sh, islast;

    const float4* src = reinterpret_cast<const float4*>(lc + (size_t)b * Pn);
    for (int i = tid; i < Pn / 4; i += 1024) reinterpret_cast<float4*>(s)[i] = src[i];
    if (tid < 64) {  // wave 0 reduces num_pos over this batch's PX partials
        int npl = (tid < PX) ? part_np[b * PX + tid] : 0;
        for (int off = 32; off > 0; off >>= 1) npl += __shfl_down(npl, off);
        if (tid == 0) np_sh = npl;
    }
    __syncthreads();
    const int k = min(3 * np_sh, Pn - 1);

    unsigned lo = 0u, hi = 0x7F800000u;
#pragma unroll 1
    for (int it = 0; it < 31; ++it) {
        const unsigned mid = lo + ((hi - lo) >> 1);
        const float fm = __uint_as_float(mid);
        int c = 0;
        for (int i = tid; i < Pn / 4; i += 1024) {
            const float4 v = reinterpret_cast<const float4*>(s)[i];
            c += (v.x >= fm) + (v.y >= fm) + (v.z >= fm) + (v.w >= fm);
        }
        for (int off = 32; off > 0; off >>= 1) c += __shfl_down(c, off);
        if (lane == 0) redc[it & 1][wid] = c;
        __syncthreads();  // also separates this iter's writes from prior iter's reads
        int tot = 0;
#pragma unroll
        for (int w = 0; w < Wn; ++w) tot += redc[it & 1][w];  // broadcast reads
        if (tot >= k) lo = mid;
        else hi = mid;
    }
    const float v = __uint_as_float(lo);  // exact k-th largest value

    float sm = 0.0f;
    int c = 0;
    for (int i = tid; i < Pn / 4; i += 1024) {
        const float4 q = reinterpret_cast<const float4*>(s)[i];
        if (q.x > v) { sm += q.x; ++c; }
        if (q.y > v) { sm += q.y; ++c; }
        if (q.z > v) { sm += q.z; ++c; }
        if (q.w > v) { sm += q.w; ++c; }
    }
    for (int off = 32; off > 0; off >>= 1) {
        sm += __shfl_down(sm, off);
        c += __shfl_down(c, off);
    }
    if (lane == 0) { redf[wid] = sm; redi[wid] = c; }
    __syncthreads();
    if (tid == 0) {
        float st = 0.0f;
        int ct = 0;
#pragma unroll
        for (int w = 0; w < Wn; ++w) { st += redf[w]; ct += redi[w]; }
        negsum[b] = st + (float)(k - ct) * v;  // exact tie handling at boundary
        __threadfence();
        islast = (atomicAdd(done, 1) == Bn - 1) ? 1 : 0;
    }
    __syncthreads();
    if (!islast) return;
    __threadfence();  // acquire: other blocks' stores precede their fenced atomics

    // ---- fused final reduce (exactly one block runs this) ----
    float sl = 0.0f, sn = 0.0f;
    int np = 0;
    for (int i = tid; i < Bn * PX; i += 1024) {
        sl += part_loc[i];
        sn += part_nll[i];
        np += part_np[i];
    }
    if (tid < Bn) sn += negsum[tid];
    for (int off = 32; off > 0; off >>= 1) {
        sl += __shfl_down(sl, off);
        sn += __shfl_down(sn, off);
        np += __shfl_down(np, off);
    }
    if (lane == 0) { redf[wid] = sn; redf2[wid] = sl; redi[wid] = np; }
    __syncthreads();
    if (tid == 0) {
        float tsl = 0.0f, tsn = 0.0f;
        int tnp = 0;
#pragma unroll
        for (int w = 0; w < Wn; ++w) { tsl += redf2[w]; tsn += redf[w]; tnp += redi[w]; }
        const float fN = (float)tnp;
        out[0] = tsl / fN;
        out[1] = tsn / fN;
    }
}

extern "C" void kernel_launch(void* const* d_in, const int* in_sizes, int n_in,
                              void* d_out, int out_size, void* d_ws, size_t ws_size,
                              hipStream_t stream) {
    const float* conf = (const float*)d_in[0];
    const float* loc = (const float*)d_in[1];
    const float* priors = (const float*)d_in[2];
    const float* labels = (const float*)d_in[3];
    const int* objc = (const int*)d_in[4];
    float* out = (float*)d_out;

    // ws layout (4B units): part_loc[2240] | part_nll[2240] | part_np[2240] |
    //                       negsum[64] | bp[3200] | lc[B*P] | done[1]
    float* part_loc = (float*)d_ws;
    float* part_nll = part_loc + Bn * PX;
    int* part_np = (int*)(part_nll + Bn * PX);
    float* negsum = (float*)(part_np + Bn * PX);
    int* bp = (int*)(negsum + Bn);
    float* lc = (float*)(bp + Bn * NMAXn);
    int* done = (int*)(lc + (size_t)Bn * Pn);

    k_bp<<<Bn, 1024, 0, stream>>>(labels, objc, priors, bp);
    dim3 g(PX, Bn);
    k_main<<<g, 256, 0, stream>>>(conf, loc, priors, labels, objc, bp, lc,
                                  part_loc, part_nll, part_np, done);
    k_neg<<<Bn, 1024, 0, stream>>>(lc, part_loc, part_nll, part_np, negsum, done, out);
}

// Round 5
// 129.889 us; speedup vs baseline: 1.3914x; 1.3914x over previous
//
#include <hip/hip_runtime.h>
#include <math.h>

#define Bn 64
#define Pn 8732
#define Cn 21
#define NMAXn 50
#define PX 35  // ceil(Pn/256)

// ---------------------------------------------------------------------------
// K1: best-prior partials. Grid (PX, Bn), 256 threads, one prior per thread.
// Priors read coalesced from global (9 MB total vs R4's 437 MB / R4's 64-block
// serialization). Per n: IoU + wave shfl-reduce; per-wave winners in LDS; one
// sync; 4-slot combine -> per-tile winner (v, p). First-max tie-break kept:
// strict > over ascending p within wave, ascending wave id in combine.
// ---------------------------------------------------------------------------
__global__ __launch_bounds__(256) void k_bpp(const float* __restrict__ labels,
                                             const int* __restrict__ objc,
                                             const float* __restrict__ priors,
                                             float* __restrict__ bpv,
                                             int* __restrict__ bpi) {
    const int b = blockIdx.y;
    const int px = blockIdx.x;
    const int tid = threadIdx.x;
    const int lane = tid & 63, wid = tid >> 6;
    const int p = px * 256 + tid;
    const bool valid = p < Pn;
    __shared__ float lab[NMAXn * 5];
    __shared__ int cnt_s;
    __shared__ float wv[NMAXn][4];
    __shared__ int wi[NMAXn][4];
    for (int i = tid; i < NMAXn * 5; i += 256) lab[i] = labels[b * NMAXn * 5 + i];
    if (tid == 0) cnt_s = objc[b];
    __syncthreads();
    const int pc = valid ? p : (Pn - 1);
    const float4 pr = reinterpret_cast<const float4*>(priors)[pc];
    const float px0 = pr.x - 0.5f * pr.z, py0 = pr.y - 0.5f * pr.w;
    const float px1 = pr.x + 0.5f * pr.z, py1 = pr.y + 0.5f * pr.w;
    const float parea = (px1 - px0) * (py1 - py0);
    const int cnt = cnt_s;
    for (int n = 0; n < cnt; ++n) {
        const float gx0 = lab[n * 5 + 0], gy0 = lab[n * 5 + 1];
        const float gx1 = lab[n * 5 + 2], gy1 = lab[n * 5 + 3];
        const float lx = fmaxf(gx0, px0), ly = fmaxf(gy0, py0);
        const float rx = fminf(gx1, px1), ry = fminf(gy1, py1);
        const float w = fmaxf(rx - lx, 0.0f), h = fmaxf(ry - ly, 0.0f);
        const float inter = w * h;
        const float ga = (gx1 - gx0) * (gy1 - gy0);
        float v = inter / (ga + parea - inter);
        if (!valid) v = -2.0f;
        int idx = p;
        for (int off = 32; off > 0; off >>= 1) {
            const float ov = __shfl_down(v, off);
            const int oi = __shfl_down(idx, off);
            if (ov > v || (ov == v && oi < idx)) { v = ov; idx = oi; }
        }
        if (lane == 0) { wv[n][wid] = v; wi[n][wid] = idx; }
    }
    __syncthreads();
    if (tid < cnt) {
        float v = wv[tid][0];
        int idx = wi[tid][0];
#pragma unroll
        for (int w = 1; w < 4; ++w) {
            const float ov = wv[tid][w];
            const int oi = wi[tid][w];
            if (ov > v) { v = ov; idx = oi; }  // ascending wid: tie keeps earlier
        }
        const int g = (b * NMAXn + tid) * PX + px;
        bpv[g] = v;
        bpi[g] = idx;
    }
}

// ---------------------------------------------------------------------------
// K2: reduce the PX tile winners per (b,n) -> bp[b][n]. Ascending tile order
// with strict > preserves the global first-max index exactly.
// ---------------------------------------------------------------------------
__global__ __launch_bounds__(64) void k_bpr(const int* __restrict__ objc,
                                            const float* __restrict__ bpv,
                                            const int* __restrict__ bpi,
                                            int* __restrict__ bp) {
    const int b = blockIdx.x;
    const int n = threadIdx.x;
    if (n >= objc[b]) return;
    const int g0 = (b * NMAXn + n) * PX;
    float v = bpv[g0];
    int idx = bpi[g0];
    for (int t = 1; t < PX; ++t) {
        const float ov = bpv[g0 + t];
        if (ov > v) { v = ov; idx = bpi[g0 + t]; }
    }
    bp[b * NMAXn + n] = idx;
}

// ---------------------------------------------------------------------------
// K3: main pass. Best-GT match computed INLINE (merged with forced-override
// scan): forced (last n with bp[n]==p) takes precedence over IoU argmax,
// matching the reference scatter. Then lse, nll, fused smooth-L1, pos-masked
// mining score lc, per-block partials via plain stores. Block (0,0) resets
// the done counter for K4.
// ---------------------------------------------------------------------------
__global__ __launch_bounds__(256) void k_main(const float* __restrict__ conf,
                                              const float* __restrict__ loc,
                                              const float* __restrict__ priors,
                                              const float* __restrict__ labels,
                                              const int* __restrict__ objc,
                                              const int* __restrict__ bp,
                                              float* __restrict__ lc,
                                              float* __restrict__ part_loc,
                                              float* __restrict__ part_nll,
                                              int* __restrict__ part_np,
                                              int* __restrict__ done) {
    const int b = blockIdx.y;
    const int px = blockIdx.x;
    const int p0 = px * 256;
    const int tid = threadIdx.x;
    const int rows = min(256, Pn - p0);
    const int p = p0 + ((tid < rows) ? tid : 0);
    const size_t gi = (size_t)b * Pn + p;

    if (b == 0 && px == 0 && tid == 0) *done = 0;  // ordered before K4 by kernel boundary

    __shared__ float sconf[256 * Cn];
    __shared__ float lab[NMAXn * 5];
    __shared__ int sbp[NMAXn];
    __shared__ int cnt_s;
    const float4* src = reinterpret_cast<const float4*>(conf + ((size_t)b * Pn + p0) * Cn);
    const int n4 = rows * Cn / 4;  // rows*21 divisible by 4 for rows in {256,28}
    for (int i = tid; i < n4; i += 256) reinterpret_cast<float4*>(sconf)[i] = src[i];
    for (int i = tid; i < NMAXn * 5; i += 256) lab[i] = labels[b * NMAXn * 5 + i];
    if (tid < NMAXn) sbp[tid] = bp[b * NMAXn + tid];
    if (tid == 0) cnt_s = objc[b];
    __syncthreads();

    float my_loc = 0.0f, my_nll = 0.0f;
    int my_np = 0;
    if (tid < rows) {
        const int cnt = cnt_s;
        const float4 pr = reinterpret_cast<const float4*>(priors)[p];
        const float px0 = pr.x - 0.5f * pr.z, py0 = pr.y - 0.5f * pr.w;
        const float px1 = pr.x + 0.5f * pr.z, py1 = pr.y + 0.5f * pr.w;
        const float parea = (px1 - px0) * (py1 - py0);
        float best = -1.0f;
        int bidx = 0, fidx = -1;
        for (int n = 0; n < cnt; ++n) {
            const float gx0 = lab[n * 5 + 0], gy0 = lab[n * 5 + 1];
            const float gx1 = lab[n * 5 + 2], gy1 = lab[n * 5 + 3];
            const float lx = fmaxf(gx0, px0), ly = fmaxf(gy0, py0);
            const float rx = fminf(gx1, px1), ry = fminf(gy1, py1);
            const float w = fmaxf(rx - lx, 0.0f), h = fmaxf(ry - ly, 0.0f);
            const float inter = w * h;
            const float ga = (gx1 - gx0) * (gy1 - gy0);
            const float v = inter / (ga + parea - inter);
            if (v > best) { best = v; bidx = n; }  // strict >: first-occurrence argmax
            if (sbp[n] == p) fidx = n;             // ascending: last forced n wins
        }
        const int ti = (fidx >= 0) ? fidx : bidx;
        const int fl = (fidx >= 0) || (best >= 0.5f);
        const int ct = fl ? ((int)lab[ti * 5 + 4] + 1) : 0;
        const float* row = sconf + tid * Cn;  // stride 21: odd -> conflict-benign
        float m = row[0];
#pragma unroll
        for (int j = 1; j < Cn; ++j) m = fmaxf(m, row[j]);
        float s2 = 0.0f;
#pragma unroll
        for (int j = 0; j < Cn; ++j) s2 += __expf(row[j] - m);
        const float nll = __logf(s2) + m - row[ct];
        if (ct > 0) {
            lc[gi] = 0.0f;
            my_np = 1;
            my_nll = nll;
            const float gx0 = lab[ti * 5 + 0], gy0 = lab[ti * 5 + 1];
            const float gx1 = lab[ti * 5 + 2], gy1 = lab[ti * 5 + 3];
            const float tx = ((gx0 + gx1) * 0.5f - pr.x) / (0.1f * pr.z);
            const float ty = ((gy0 + gy1) * 0.5f - pr.y) / (0.1f * pr.w);
            const float tw = __logf((gx1 - gx0) / pr.z) * 5.0f;  // /0.2
            const float th = __logf((gy1 - gy0) / pr.w) * 5.0f;
            const float4 l = reinterpret_cast<const float4*>(loc)[gi];
            float d;
            d = fabsf(l.x - tx); my_loc += (d < 1.0f) ? 0.5f * d * d : d - 0.5f;
            d = fabsf(l.y - ty); my_loc += (d < 1.0f) ? 0.5f * d * d : d - 0.5f;
            d = fabsf(l.z - tw); my_loc += (d < 1.0f) ? 0.5f * d * d : d - 0.5f;
            d = fabsf(l.w - th); my_loc += (d < 1.0f) ? 0.5f * d * d : d - 0.5f;
        } else {
            lc[gi] = nll;
        }
    }
    for (int off = 32; off > 0; off >>= 1) {
        my_loc += __shfl_down(my_loc, off);
        my_nll += __shfl_down(my_nll, off);
        my_np += __shfl_down(my_np, off);
    }
    __shared__ float rl[4], rn[4];
    __shared__ int rp[4];
    const int wid = tid >> 6, lane = tid & 63;
    if (lane == 0) { rl[wid] = my_loc; rn[wid] = my_nll; rp[wid] = my_np; }
    __syncthreads();
    if (tid == 0) {
        const int g = b * PX + px;
        part_loc[g] = rl[0] + rl[1] + rl[2] + rl[3];
        part_nll[g] = rn[0] + rn[1] + rn[2] + rn[3];
        part_np[g] = rp[0] + rp[1] + rp[2] + rp[3];
    }
}

// ---------------------------------------------------------------------------
// K4: per-batch hard-negative top-k sum. 1024 threads, bisection on float
// bits (31 iters, exact); one sync/iter via parity-buffered per-wave slots.
// Fused final reduce via done counter (last of 64 blocks writes out).
// ---------------------------------------------------------------------------
#define Wn 16
__global__ __launch_bounds__(1024) void k_neg(const float* __restrict__ lc,
                                              const float* __restrict__ part_loc,
                                              const float* __restrict__ part_nll,
                                              const int* __restrict__ part_np,
                                              float* __restrict__ negsum,
                                              int* __restrict__ done,
                                              float* __restrict__ out) {
    const int b = blockIdx.x;
    const int tid = threadIdx.x;
    const int lane = tid & 63, wid = tid >> 6;
    __shared__ float s[Pn];  // 34928 B
    __shared__ int redc[2][Wn];
    __shared__ float redf[Wn], redf2[Wn];
    __shared__ int redi[Wn];
    __shared__ int np_sh, islast;

    const float4* src = reinterpret_cast<const float4*>(lc + (size_t)b * Pn);
    for (int i = tid; i < Pn / 4; i += 1024) reinterpret_cast<float4*>(s)[i] = src[i];
    if (tid < 64) {  // wave 0 reduces num_pos over this batch's PX partials
        int npl = (tid < PX) ? part_np[b * PX + tid] : 0;
        for (int off = 32; off > 0; off >>= 1) npl += __shfl_down(npl, off);
        if (tid == 0) np_sh = npl;
    }
    __syncthreads();
    const int k = min(3 * np_sh, Pn - 1);

    unsigned lo = 0u, hi = 0x7F800000u;
#pragma unroll 1
    for (int it = 0; it < 31; ++it) {
        const unsigned mid = lo + ((hi - lo) >> 1);
        const float fm = __uint_as_float(mid);
        int c = 0;
        for (int i = tid; i < Pn / 4; i += 1024) {
            const float4 v = reinterpret_cast<const float4*>(s)[i];
            c += (v.x >= fm) + (v.y >= fm) + (v.z >= fm) + (v.w >= fm);
        }
        for (int off = 32; off > 0; off >>= 1) c += __shfl_down(c, off);
        if (lane == 0) redc[it & 1][wid] = c;
        __syncthreads();
        int tot = 0;
#pragma unroll
        for (int w = 0; w < Wn; ++w) tot += redc[it & 1][w];  // broadcast reads
        if (tot >= k) lo = mid;
        else hi = mid;
    }
    const float v = __uint_as_float(lo);  // exact k-th largest value

    float sm = 0.0f;
    int c = 0;
    for (int i = tid; i < Pn / 4; i += 1024) {
        const float4 q = reinterpret_cast<const float4*>(s)[i];
        if (q.x > v) { sm += q.x; ++c; }
        if (q.y > v) { sm += q.y; ++c; }
        if (q.z > v) { sm += q.z; ++c; }
        if (q.w > v) { sm += q.w; ++c; }
    }
    for (int off = 32; off > 0; off >>= 1) {
        sm += __shfl_down(sm, off);
        c += __shfl_down(c, off);
    }
    if (lane == 0) { redf[wid] = sm; redi[wid] = c; }
    __syncthreads();
    if (tid == 0) {
        float st = 0.0f;
        int ct = 0;
#pragma unroll
        for (int w = 0; w < Wn; ++w) { st += redf[w]; ct += redi[w]; }
        negsum[b] = st + (float)(k - ct) * v;  // exact tie handling at boundary
        __threadfence();
        islast = (atomicAdd(done, 1) == Bn - 1) ? 1 : 0;
    }
    __syncthreads();
    if (!islast) return;
    __threadfence();  // acquire: other blocks' stores precede their fenced atomics

    // ---- fused final reduce (exactly one block runs this) ----
    float sl = 0.0f, sn = 0.0f;
    int np = 0;
    for (int i = tid; i < Bn * PX; i += 1024) {
        sl += part_loc[i];
        sn += part_nll[i];
        np += part_np[i];
    }
    if (tid < Bn) sn += negsum[tid];
    for (int off = 32; off > 0; off >>= 1) {
        sl += __shfl_down(sl, off);
        sn += __shfl_down(sn, off);
        np += __shfl_down(np, off);
    }
    if (lane == 0) { redf[wid] = sn; redf2[wid] = sl; redi[wid] = np; }
    __syncthreads();
    if (tid == 0) {
        float tsl = 0.0f, tsn = 0.0f;
        int tnp = 0;
#pragma unroll
        for (int w = 0; w < Wn; ++w) { tsl += redf2[w]; tsn += redf[w]; tnp += redi[w]; }
        const float fN = (float)tnp;
        out[0] = tsl / fN;
        out[1] = tsn / fN;
    }
}

extern "C" void kernel_launch(void* const* d_in, const int* in_sizes, int n_in,
                              void* d_out, int out_size, void* d_ws, size_t ws_size,
                              hipStream_t stream) {
    const float* conf = (const float*)d_in[0];
    const float* loc = (const float*)d_in[1];
    const float* priors = (const float*)d_in[2];
    const float* labels = (const float*)d_in[3];
    const int* objc = (const int*)d_in[4];
    float* out = (float*)d_out;

    // ws layout (4B units): part_loc[2240] | part_nll[2240] | part_np[2240] |
    //   negsum[64] | bp[3200] | bpv[112000] | bpi[112000] | lc[B*P] | done[1]
    float* part_loc = (float*)d_ws;
    float* part_nll = part_loc + Bn * PX;
    int* part_np = (int*)(part_nll + Bn * PX);
    float* negsum = (float*)(part_np + Bn * PX);
    int* bp = (int*)(negsum + Bn);
    float* bpv = (float*)(bp + Bn * NMAXn);
    int* bpi = (int*)(bpv + Bn * NMAXn * PX);
    float* lc = (float*)(bpi + Bn * NMAXn * PX);
    int* done = (int*)(lc + (size_t)Bn * Pn);

    dim3 g(PX, Bn);
    k_bpp<<<g, 256, 0, stream>>>(labels, objc, priors, bpv, bpi);
    k_bpr<<<Bn, 64, 0, stream>>>(objc, bpv, bpi, bp);
    k_main<<<g, 256, 0, stream>>>(conf, loc, priors, labels, objc, bp, lc,
                                  part_loc, part_nll, part_np, done);
    k_neg<<<Bn, 1024, 0, stream>>>(lc, part_loc, part_nll, part_np, negsum, done, out);
}

// Round 6
// 86.754 us; speedup vs baseline: 2.0832x; 1.4972x over previous
//
#include <hip/hip_runtime.h>
#include <math.h>

#define Bn 64
#define Pn 8732
#define Cn 21
#define NMAXn 50
#define PX 35  // ceil(Pn/256)
#define Wn 16  // waves in a 1024-thread block

// ---------------------------------------------------------------------------
// K1: best-prior partials. Grid (PX, Bn), 256 threads. Tile's 256 priors
// staged in LDS (corner form). GTs split across the 4 waves (n = wid::4).
// Per GT: each lane serially accumulates 4 priors (no cross-lane), then ONE
// 6-step shfl cascade -> per-tile winner. 4x fewer cascades than R5 and each
// is amortized over 4x more IoU work. Invalid tail priors get box {3,3,3,3}
// (IoU = 0, largest indices) so they never win first-max ties.
// ---------------------------------------------------------------------------
__global__ __launch_bounds__(256) void k_bpp(const float* __restrict__ labels,
                                             const int* __restrict__ objc,
                                             const float* __restrict__ priors,
                                             float* __restrict__ bpv,
                                             int* __restrict__ bpi) {
    const int b = blockIdx.y;
    const int px = blockIdx.x;
    const int tid = threadIdx.x;
    const int lane = tid & 63, wid = tid >> 6;
    const int p = px * 256 + tid;
    __shared__ float4 pc[256];        // corner-form tile priors
    __shared__ float lab[NMAXn * 5];
    __shared__ int cnt_s;
    {
        const int pcl = (p < Pn) ? p : (Pn - 1);
        const float4 pr = reinterpret_cast<const float4*>(priors)[pcl];
        float4 c = make_float4(pr.x - 0.5f * pr.z, pr.y - 0.5f * pr.w,
                               pr.x + 0.5f * pr.z, pr.y + 0.5f * pr.w);
        if (p >= Pn) c = make_float4(3.0f, 3.0f, 3.0f, 3.0f);  // IoU == 0 vs any GT
        pc[tid] = c;
    }
    for (int i = tid; i < NMAXn * 5; i += 256) lab[i] = labels[b * NMAXn * 5 + i];
    if (tid == 0) cnt_s = objc[b];
    __syncthreads();
    const int cnt = cnt_s;
    for (int n = wid; n < cnt; n += 4) {
        const float gx0 = lab[n * 5 + 0], gy0 = lab[n * 5 + 1];
        const float gx1 = lab[n * 5 + 2], gy1 = lab[n * 5 + 3];
        const float ga = (gx1 - gx0) * (gy1 - gy0);
        float best = -1.0f;
        int bidx = 0;
#pragma unroll
        for (int j = 0; j < 4; ++j) {  // ascending local idx: strict > keeps min p
            const float4 c = pc[lane + 64 * j];
            const float lx = fmaxf(gx0, c.x), ly = fmaxf(gy0, c.y);
            const float rx = fminf(gx1, c.z), ry = fminf(gy1, c.w);
            const float w = fmaxf(rx - lx, 0.0f), h = fmaxf(ry - ly, 0.0f);
            const float inter = w * h;
            const float pa = (c.z - c.x) * (c.w - c.y);
            const float v = inter / (ga + pa - inter);
            if (v > best) { best = v; bidx = px * 256 + lane + 64 * j; }
        }
        for (int off = 32; off > 0; off >>= 1) {
            const float ov = __shfl_down(best, off);
            const int oi = __shfl_down(bidx, off);
            if (ov > best || (ov == best && oi < bidx)) { best = ov; bidx = oi; }
        }
        if (lane == 0) {
            const int g = (b * NMAXn + n) * PX + px;
            bpv[g] = best;
            bpi[g] = bidx;
        }
    }
}

// ---------------------------------------------------------------------------
// K2: reduce the PX tile winners per (b,n) -> bp[b][n]. Ascending tile order
// with strict > preserves the global first-max index exactly. Fixed 35-iter
// loop unrolls; loads are independent (latency overlapped).
// ---------------------------------------------------------------------------
__global__ __launch_bounds__(64) void k_bpr(const int* __restrict__ objc,
                                            const float* __restrict__ bpv,
                                            const int* __restrict__ bpi,
                                            int* __restrict__ bp) {
    const int b = blockIdx.x;
    const int n = threadIdx.x;
    if (n >= objc[b]) return;
    const int g0 = (b * NMAXn + n) * PX;
    float v = bpv[g0];
    int idx = bpi[g0];
#pragma unroll
    for (int t = 1; t < PX; ++t) {
        const float ov = bpv[g0 + t];
        if (ov > v) { v = ov; idx = bpi[g0 + t]; }
    }
    bp[b * NMAXn + n] = idx;
}

// ---------------------------------------------------------------------------
// K3: main pass. Best-GT match computed INLINE (merged with forced-override
// scan): forced (last n with bp[n]==p) takes precedence over IoU argmax,
// matching the reference scatter. Then lse, nll, fused smooth-L1, pos-masked
// mining score lc, per-block partials via plain stores. Block (0,0) resets
// the done counter for K4.
// ---------------------------------------------------------------------------
__global__ __launch_bounds__(256) void k_main(const float* __restrict__ conf,
                                              const float* __restrict__ loc,
                                              const float* __restrict__ priors,
                                              const float* __restrict__ labels,
                                              const int* __restrict__ objc,
                                              const int* __restrict__ bp,
                                              float* __restrict__ lc,
                                              float* __restrict__ part_loc,
                                              float* __restrict__ part_nll,
                                              int* __restrict__ part_np,
                                              int* __restrict__ done) {
    const int b = blockIdx.y;
    const int px = blockIdx.x;
    const int p0 = px * 256;
    const int tid = threadIdx.x;
    const int rows = min(256, Pn - p0);
    const int p = p0 + ((tid < rows) ? tid : 0);
    const size_t gi = (size_t)b * Pn + p;

    if (b == 0 && px == 0 && tid == 0) *done = 0;  // ordered before K4 by kernel boundary

    __shared__ float sconf[256 * Cn];
    __shared__ float lab[NMAXn * 5];
    __shared__ int sbp[NMAXn];
    __shared__ int cnt_s;
    const float4* src = reinterpret_cast<const float4*>(conf + ((size_t)b * Pn + p0) * Cn);
    const int n4 = rows * Cn / 4;  // rows*21 divisible by 4 for rows in {256,28}
    for (int i = tid; i < n4; i += 256) reinterpret_cast<float4*>(sconf)[i] = src[i];
    for (int i = tid; i < NMAXn * 5; i += 256) lab[i] = labels[b * NMAXn * 5 + i];
    if (tid < NMAXn) sbp[tid] = bp[b * NMAXn + tid];
    if (tid == 0) cnt_s = objc[b];
    __syncthreads();

    float my_loc = 0.0f, my_nll = 0.0f;
    int my_np = 0;
    if (tid < rows) {
        const int cnt = cnt_s;
        const float4 pr = reinterpret_cast<const float4*>(priors)[p];
        const float px0 = pr.x - 0.5f * pr.z, py0 = pr.y - 0.5f * pr.w;
        const float px1 = pr.x + 0.5f * pr.z, py1 = pr.y + 0.5f * pr.w;
        const float parea = (px1 - px0) * (py1 - py0);
        float best = -1.0f;
        int bidx = 0, fidx = -1;
        for (int n = 0; n < cnt; ++n) {
            const float gx0 = lab[n * 5 + 0], gy0 = lab[n * 5 + 1];
            const float gx1 = lab[n * 5 + 2], gy1 = lab[n * 5 + 3];
            const float lx = fmaxf(gx0, px0), ly = fmaxf(gy0, py0);
            const float rx = fminf(gx1, px1), ry = fminf(gy1, py1);
            const float w = fmaxf(rx - lx, 0.0f), h = fmaxf(ry - ly, 0.0f);
            const float inter = w * h;
            const float ga = (gx1 - gx0) * (gy1 - gy0);
            const float v = inter / (ga + parea - inter);
            if (v > best) { best = v; bidx = n; }  // strict >: first-occurrence argmax
            if (sbp[n] == p) fidx = n;             // ascending: last forced n wins
        }
        const int ti = (fidx >= 0) ? fidx : bidx;
        const int fl = (fidx >= 0) || (best >= 0.5f);
        const int ct = fl ? ((int)lab[ti * 5 + 4] + 1) : 0;
        const float* row = sconf + tid * Cn;  // stride 21: odd -> conflict-benign
        float m = row[0];
#pragma unroll
        for (int j = 1; j < Cn; ++j) m = fmaxf(m, row[j]);
        float s2 = 0.0f;
#pragma unroll
        for (int j = 0; j < Cn; ++j) s2 += __expf(row[j] - m);
        const float nll = __logf(s2) + m - row[ct];
        if (ct > 0) {
            lc[gi] = 0.0f;
            my_np = 1;
            my_nll = nll;
            const float gx0 = lab[ti * 5 + 0], gy0 = lab[ti * 5 + 1];
            const float gx1 = lab[ti * 5 + 2], gy1 = lab[ti * 5 + 3];
            const float tx = ((gx0 + gx1) * 0.5f - pr.x) / (0.1f * pr.z);
            const float ty = ((gy0 + gy1) * 0.5f - pr.y) / (0.1f * pr.w);
            const float tw = __logf((gx1 - gx0) / pr.z) * 5.0f;  // /0.2
            const float th = __logf((gy1 - gy0) / pr.w) * 5.0f;
            const float4 l = reinterpret_cast<const float4*>(loc)[gi];
            float d;
            d = fabsf(l.x - tx); my_loc += (d < 1.0f) ? 0.5f * d * d : d - 0.5f;
            d = fabsf(l.y - ty); my_loc += (d < 1.0f) ? 0.5f * d * d : d - 0.5f;
            d = fabsf(l.z - tw); my_loc += (d < 1.0f) ? 0.5f * d * d : d - 0.5f;
            d = fabsf(l.w - th); my_loc += (d < 1.0f) ? 0.5f * d * d : d - 0.5f;
        } else {
            lc[gi] = nll;
        }
    }
    for (int off = 32; off > 0; off >>= 1) {
        my_loc += __shfl_down(my_loc, off);
        my_nll += __shfl_down(my_nll, off);
        my_np += __shfl_down(my_np, off);
    }
    __shared__ float rl[4], rn[4];
    __shared__ int rp[4];
    const int wid = tid >> 6, lane = tid & 63;
    if (lane == 0) { rl[wid] = my_loc; rn[wid] = my_nll; rp[wid] = my_np; }
    __syncthreads();
    if (tid == 0) {
        const int g = b * PX + px;
        part_loc[g] = rl[0] + rl[1] + rl[2] + rl[3];
        part_nll[g] = rn[0] + rn[1] + rn[2] + rn[3];
        part_np[g] = rp[0] + rp[1] + rp[2] + rp[3];
    }
}

// ---------------------------------------------------------------------------
// K4: per-batch hard-negative top-k sum. 1024 threads; the batch's 8732
// scores live in REGISTERS (3 float4/thread, sentinel -1 for tail) so each
// bisection iter is 12 register compares + one block reduce + one sync.
// Bisection on float bits (31 iters, exact, lc >= 0). Fused final reduce via
// done counter (last of 64 blocks reduces partials and writes out).
// ---------------------------------------------------------------------------
__global__ __launch_bounds__(1024) void k_neg(const float* __restrict__ lc,
                                              const float* __restrict__ part_loc,
                                              const float* __restrict__ part_nll,
                                              const int* __restrict__ part_np,
                                              float* __restrict__ negsum,
                                              int* __restrict__ done,
                                              float* __restrict__ out) {
    const int b = blockIdx.x;
    const int tid = threadIdx.x;
    const int lane = tid & 63, wid = tid >> 6;
    __shared__ int redc[2][Wn];
    __shared__ float redf[Wn], redf2[Wn];
    __shared__ int redi[Wn];
    __shared__ int np_sh, islast;

    const int NV = Pn / 4;  // 2183 float4s exactly
    const float4* src = reinterpret_cast<const float4*>(lc + (size_t)b * Pn);
    const float4 sent = make_float4(-1.0f, -1.0f, -1.0f, -1.0f);
    float4 r0 = (tid < NV) ? src[tid] : sent;
    float4 r1 = (tid + 1024 < NV) ? src[tid + 1024] : sent;
    float4 r2 = (tid + 2048 < NV) ? src[tid + 2048] : sent;

    if (tid < 64) {  // wave 0 reduces num_pos over this batch's PX partials
        int npl = (tid < PX) ? part_np[b * PX + tid] : 0;
        for (int off = 32; off > 0; off >>= 1) npl += __shfl_down(npl, off);
        if (tid == 0) np_sh = npl;
    }
    __syncthreads();
    const int k = min(3 * np_sh, Pn - 1);

    unsigned lo = 0u, hi = 0x7F800000u;
#pragma unroll 1
    for (int it = 0; it < 31; ++it) {
        const unsigned mid = lo + ((hi - lo) >> 1);
        const float fm = __uint_as_float(mid);  // fm >= 0: sentinels never counted
        int c = (r0.x >= fm) + (r0.y >= fm) + (r0.z >= fm) + (r0.w >= fm)
              + (r1.x >= fm) + (r1.y >= fm) + (r1.z >= fm) + (r1.w >= fm)
              + (r2.x >= fm) + (r2.y >= fm) + (r2.z >= fm) + (r2.w >= fm);
        for (int off = 32; off > 0; off >>= 1) c += __shfl_down(c, off);
        if (lane == 0) redc[it & 1][wid] = c;
        __syncthreads();
        int tot = 0;
#pragma unroll
        for (int w = 0; w < Wn; ++w) tot += redc[it & 1][w];  // broadcast reads
        if (tot >= k) lo = mid;
        else hi = mid;
    }
    const float v = __uint_as_float(lo);  // exact k-th largest value (v >= 0)

    float sm = 0.0f;
    int c = 0;
    if (r0.x > v) { sm += r0.x; ++c; }
    if (r0.y > v) { sm += r0.y; ++c; }
    if (r0.z > v) { sm += r0.z; ++c; }
    if (r0.w > v) { sm += r0.w; ++c; }
    if (r1.x > v) { sm += r1.x; ++c; }
    if (r1.y > v) { sm += r1.y; ++c; }
    if (r1.z > v) { sm += r1.z; ++c; }
    if (r1.w > v) { sm += r1.w; ++c; }
    if (r2.x > v) { sm += r2.x; ++c; }
    if (r2.y > v) { sm += r2.y; ++c; }
    if (r2.z > v) { sm += r2.z; ++c; }
    if (r2.w > v) { sm += r2.w; ++c; }
    for (int off = 32; off > 0; off >>= 1) {
        sm += __shfl_down(sm, off);
        c += __shfl_down(c, off);
    }
    if (lane == 0) { redf[wid] = sm; redi[wid] = c; }
    __syncthreads();
    if (tid == 0) {
        float st = 0.0f;
        int ct = 0;
#pragma unroll
        for (int w = 0; w < Wn; ++w) { st += redf[w]; ct += redi[w]; }
        negsum[b] = st + (float)(k - ct) * v;  // exact tie handling at boundary
        __threadfence();
        islast = (atomicAdd(done, 1) == Bn - 1) ? 1 : 0;
    }
    __syncthreads();
    if (!islast) return;
    __threadfence();  // acquire: other blocks' stores precede their fenced atomics

    // ---- fused final reduce (exactly one block runs this) ----
    float sl = 0.0f, sn = 0.0f;
    int np = 0;
    for (int i = tid; i < Bn * PX; i += 1024) {
        sl += part_loc[i];
        sn += part_nll[i];
        np += part_np[i];
    }
    if (tid < Bn) sn += negsum[tid];
    for (int off = 32; off > 0; off >>= 1) {
        sl += __shfl_down(sl, off);
        sn += __shfl_down(sn, off);
        np += __shfl_down(np, off);
    }
    if (lane == 0) { redf[wid] = sn; redf2[wid] = sl; redi[wid] = np; }
    __syncthreads();
    if (tid == 0) {
        float tsl = 0.0f, tsn = 0.0f;
        int tnp = 0;
#pragma unroll
        for (int w = 0; w < Wn; ++w) { tsl += redf2[w]; tsn += redf[w]; tnp += redi[w]; }
        const float fN = (float)tnp;
        out[0] = tsl / fN;
        out[1] = tsn / fN;
    }
}

extern "C" void kernel_launch(void* const* d_in, const int* in_sizes, int n_in,
                              void* d_out, int out_size, void* d_ws, size_t ws_size,
                              hipStream_t stream) {
    const float* conf = (const float*)d_in[0];
    const float* loc = (const float*)d_in[1];
    const float* priors = (const float*)d_in[2];
    const float* labels = (const float*)d_in[3];
    const int* objc = (const int*)d_in[4];
    float* out = (float*)d_out;

    // ws layout (4B units): part_loc[2240] | part_nll[2240] | part_np[2240] |
    //   negsum[64] | bp[3200] | bpv[112000] | bpi[112000] | lc[B*P] | done[1]
    float* part_loc = (float*)d_ws;
    float* part_nll = part_loc + Bn * PX;
    int* part_np = (int*)(part_nll + Bn * PX);
    float* negsum = (float*)(part_np + Bn * PX);
    int* bp = (int*)(negsum + Bn);
    float* bpv = (float*)(bp + Bn * NMAXn);
    int* bpi = (int*)(bpv + Bn * NMAXn * PX);
    float* lc = (float*)(bpi + Bn * NMAXn * PX);
    int* done = (int*)(lc + (size_t)Bn * Pn);

    dim3 g(PX, Bn);
    k_bpp<<<g, 256, 0, stream>>>(labels, objc, priors, bpv, bpi);
    k_bpr<<<Bn, 64, 0, stream>>>(objc, bpv, bpi, bp);
    k_main<<<g, 256, 0, stream>>>(conf, loc, priors, labels, objc, bp, lc,
                                  part_loc, part_nll, part_np, done);
    k_neg<<<Bn, 1024, 0, stream>>>(lc, part_loc, part_nll, part_np, negsum, done, out);
}